// Round 1
// baseline (234.479 us; speedup 1.0000x reference)
//
#include <hip/hip_runtime.h>

// VQ: B=32, C=64, H=64, W=64, N_EMBED=512
// N tokens = 32*64*64 = 131072, HW = 4096
#define C_DIM   64
#define K_CODES 512
#define HW_SZ   4096
#define N_TOK   131072

// Prep: transpose embed [C][K] -> eT [K][C], and norms[k] = ||e_k||^2.
__global__ __launch_bounds__(256) void vq_prep(const float* __restrict__ embed,
                                               float* __restrict__ eT,
                                               float* __restrict__ norms) {
    int k = blockIdx.x * blockDim.x + threadIdx.x;
    if (k >= K_CODES) return;
    float s = 0.f;
    #pragma unroll
    for (int c = 0; c < C_DIM; ++c) {
        float v = embed[c * K_CODES + k];   // coalesced across k
        eT[k * C_DIM + c] = v;
        s = fmaf(v, v, s);
    }
    norms[k] = s;
}

// Main: one thread per token. f[64] in VGPRs; k-loop reads eT rows at
// wave-uniform addresses (-> s_load + SGPR-operand v_fma).
__global__ __launch_bounds__(256) void vq_main(const float* __restrict__ x,
                                               const float* __restrict__ eT,
                                               const float* __restrict__ norms,
                                               float* __restrict__ out_qwg,
                                               float* __restrict__ out_q,
                                               float* __restrict__ out_ind) {
    const int t  = blockIdx.x * 256 + threadIdx.x;
    const int b  = t >> 12;        // t / 4096
    const int hw = t & 4095;       // t % 4096

    const float* xb = x + ((size_t)b << 18) + hw;  // b*C*HW + hw

    float f[C_DIM];
    #pragma unroll
    for (int c = 0; c < C_DIM; ++c) f[c] = xb[(size_t)c << 12];  // stride HW, coalesced

    float best = 3.402823466e+38f;
    int   bestk = 0;
    for (int k = 0; k < K_CODES; ++k) {
        const float* e = eT + (k << 6);   // wave-uniform -> scalar loads
        float d0 = 0.f, d1 = 0.f, d2 = 0.f, d3 = 0.f;
        #pragma unroll
        for (int c = 0; c < C_DIM; c += 4) {
            d0 = fmaf(f[c + 0], e[c + 0], d0);
            d1 = fmaf(f[c + 1], e[c + 1], d1);
            d2 = fmaf(f[c + 2], e[c + 2], d2);
            d3 = fmaf(f[c + 3], e[c + 3], d3);
        }
        float dot   = (d0 + d1) + (d2 + d3);
        // score = ||e||^2 - 2 f.e  ==  dist - ||f||^2 (same ordering as ref dist)
        float score = fmaf(-2.f, dot, norms[k]);
        if (score < best) { best = score; bestk = k; }  // strict < keeps FIRST min
    }

    // Gather the chosen code (per-lane index -> vector loads, L1/L2-hot 128KB table)
    const float4* eq4 = (const float4*)eT + (bestk << 4);
    float* o0 = out_qwg + ((size_t)b << 18) + hw;
    float* o1 = out_q   + ((size_t)b << 18) + hw;
    #pragma unroll
    for (int c4 = 0; c4 < 16; ++c4) {
        float4 qv = eq4[c4];
        const int cb = c4 * 4;
        float q0 = qv.x, q1 = qv.y, q2 = qv.z, q3 = qv.w;
        // faithful straight-through: x + (q - x)
        o0[(size_t)(cb + 0) << 12] = f[cb + 0] + (q0 - f[cb + 0]);
        o0[(size_t)(cb + 1) << 12] = f[cb + 1] + (q1 - f[cb + 1]);
        o0[(size_t)(cb + 2) << 12] = f[cb + 2] + (q2 - f[cb + 2]);
        o0[(size_t)(cb + 3) << 12] = f[cb + 3] + (q3 - f[cb + 3]);
        o1[(size_t)(cb + 0) << 12] = q0;
        o1[(size_t)(cb + 1) << 12] = q1;
        o1[(size_t)(cb + 2) << 12] = q2;
        o1[(size_t)(cb + 3) << 12] = q3;
    }
    out_ind[t] = (float)bestk;   // index output written as f32 (flat f32 out buffer)
}

extern "C" void kernel_launch(void* const* d_in, const int* in_sizes, int n_in,
                              void* d_out, int out_size, void* d_ws, size_t ws_size,
                              hipStream_t stream) {
    const float* x     = (const float*)d_in[0];
    const float* embed = (const float*)d_in[1];

    float* out      = (float*)d_out;
    float* out_qwg  = out;                                   // 8388608
    float* out_q    = out + (size_t)8388608;                 // 8388608
    float* out_ind  = out + (size_t)16777216;                // 131072

    float* eT    = (float*)d_ws;                 // 512*64 floats = 128 KB
    float* norms = eT + K_CODES * C_DIM;         // 512 floats

    vq_prep<<<2, 256, 0, stream>>>(embed, eT, norms);
    vq_main<<<N_TOK / 256, 256, 0, stream>>>(x, eT, norms, out_qwg, out_q, out_ind);
}